// Round 13
// baseline (552.280 us; speedup 1.0000x reference)
//
#include <hip/hip_runtime.h>
#include <hip/hip_bf16.h>

#define NN 50000
#define NPAD 50048
#define NR 8
#define NE 400000
#define CAP 32       // bucket capacity: 32 x 2B = one 64B line per (rel,node)
#define CHUNK 2048
#define CPB 196      // ceil(NE / CHUNK)
#define NRANGE 6250  // NN / 8 node-range per XCD slice
#define XBLK 12500   // NN*64/256 conversion blocks for x
#define TBLK 144     // 9 segs * 16 (64x64) transpose tiles for W

typedef __attribute__((ext_vector_type(8))) short short8v;
typedef __attribute__((ext_vector_type(4))) float f32x4;
typedef __attribute__((ext_vector_type(2))) unsigned int uint2v;

static __device__ __forceinline__ ushort f2b(float f) {
  union { float f; unsigned u; } v; v.f = f;
  unsigned u = v.u;
  unsigned r = (u + 0x7fffu + ((u >> 16) & 1u)) >> 16;
  return (ushort)r;
}
static __device__ __forceinline__ float b2f(ushort u) {
  union { unsigned u; float f; } v; v.u = ((unsigned)u) << 16;
  return v.f;
}

// ---------------- merged prep: x->bf16, W->bf16 [seg][n][k] (LDS transpose), CSR fill ----------------

__global__ __launch_bounds__(256) void k_prep(const float* __restrict__ x,
                                              const float* __restrict__ w,
                                              const float* __restrict__ lw,
                                              ushort* __restrict__ xb,
                                              ushort* __restrict__ wb,
                                              const int* __restrict__ src,
                                              const int* __restrict__ dst,
                                              int* __restrict__ cnt,
                                              ushort* __restrict__ csrp) {
  __shared__ ushort tile[64][66];  // pitch 66: transposed read stride 33 dwords (conflict-free)
  int b = blockIdx.x;
  if (b < XBLK) {
    int i = b * 256 + threadIdx.x;  // one float4 per thread
    float4 v = ((const float4*)x)[i];
    ushort4 o;
    o.x = f2b(v.x); o.y = f2b(v.y); o.z = f2b(v.z); o.w = f2b(v.w);
    ((ushort4*)xb)[i] = o;
    return;
  }
  if (b < XBLK + TBLK) {
    // W transpose: 64x64 tile, coalesced loads, coalesced stores.
    int tb = b - XBLK;
    int s = tb >> 4, t16 = tb & 15;
    int kt = (t16 >> 2) * 64, nt2 = (t16 & 3) * 64;
    const float* srcw = (s < 8) ? (w + (size_t)s * 65536) : lw;
    int t = threadIdx.x;
    #pragma unroll
    for (int i = 0; i < 16; ++i) {
      int flat = i * 256 + t;
      int kk = flat >> 6, nn = flat & 63;
      tile[kk][nn] = f2b(srcw[(size_t)(kt + kk) * 256 + nt2 + nn]);
    }
    __syncthreads();
    #pragma unroll
    for (int i = 0; i < 16; ++i) {
      int flat = i * 256 + t;
      int nn2 = flat >> 6, kk2 = flat & 63;
      wb[(size_t)s * 65536 + (size_t)(nt2 + nn2) * 256 + kt + kk2] = tile[kk2][nn2];
    }
    return;
  }
  // CSR fill: xcd slice by GLOBAL blockIdx parity (8 consecutive bids per chunk cover all 8)
  int xcd = b & 7;
  int rc = (b - XBLK - TBLK) >> 3;
  int r = rc / CPB;
  int c = rc - r * CPB;
  int nlo = xcd * NRANGE, nhi = nlo + NRANGE;
  const int* dr = dst + (size_t)r * NE;
  const int* sr = src + (size_t)r * NE;
  int e0 = c * CHUNK + threadIdx.x * 4;
  #pragma unroll
  for (int u = 0; u < CHUNK / 1024; ++u) {
    int e = e0 + u * 1024;
    if (e + 3 < NE) {
      int4 d4 = *(const int4*)(dr + e);
      int4 s4 = *(const int4*)(sr + e);
      #pragma unroll
      for (int k = 0; k < 4; ++k) {
        int d = (k == 0) ? d4.x : (k == 1) ? d4.y : (k == 2) ? d4.z : d4.w;
        int s = (k == 0) ? s4.x : (k == 1) ? s4.y : (k == 2) ? s4.z : s4.w;
        if (d >= nlo && d < nhi) {
          int slot = atomicAdd(&cnt[r * NN + d], 1);
          if (slot < CAP)
            csrp[((size_t)r * NN + d) * CAP + slot] = (ushort)s;
        }
      }
    } else {
      for (int k = 0; k < 4; ++k) {
        int e2 = e + k;
        if (e2 < NE) {
          int d = dr[e2];
          if (d >= nlo && d < nhi) {
            int slot = atomicAdd(&cnt[r * NN + d], 1);
            if (slot < CAP)
              csrp[((size_t)r * NN + d) * CAP + slot] = (ushort)sr[e2];
          }
        }
      }
    }
  }
}

// ---------------- fused gather+GEMM: BM=64 nodes x N=256, 512 threads (8 waves 2x4) ----------------
// Per seg s (0..8): gather phase (wave wid averages rows wid*8..+7 into swizzled As,
// 8 row-loads in flight per wave), then 4 kt-steps of {stage Bs, MFMA}. No xa buffer:
// each (node,seg) row is consumed by exactly this block -> zero cross-block reuse lost.
// As swizzle: byte = row*512 + (inrow ^ ((row&7)<<4)) on BOTH write and read (involution).
// Bs swizzle: r8-verified pre-swizzled gload_lds source + XOR'd ds_read.

__global__ __launch_bounds__(512, 2) void k_fused(
    const ushort* __restrict__ xb, const ushort* __restrict__ wb,
    const ushort* __restrict__ csrp, const int* __restrict__ cnt,
    const float* __restrict__ bias, float* __restrict__ out) {
  __shared__ ushort As[64 * 256];   // 32 KB
  __shared__ ushort Bs[256 * 64];   // 32 KB
  int t = threadIdx.x, lane = t & 63, wid = t >> 6;
  int wm = wid >> 2, wn = wid & 3;  // 2 x 4
  int nb = blockIdx.x * 64;

  f32x4 acc[2][4];
  #pragma unroll
  for (int a = 0; a < 2; ++a)
    #pragma unroll
    for (int b = 0; b < 4; ++b) acc[a][b] = (f32x4){0.f, 0.f, 0.f, 0.f};

  for (int s = 0; s < 9; ++s) {
    // ---- gather phase ----
    #pragma unroll 1
    for (int i = 0; i < 8; ++i) {
      int row = wid * 8 + i;
      int n = nb + row;
      unsigned wbyte = (unsigned)row * 512 + (((unsigned)lane * 8u) ^ (((unsigned)row & 7u) << 4));
      uint2v o; o[0] = 0u; o[1] = 0u;
      if (n < NN) {
        if (s == 8) {
          o = *(const uint2v*)(xb + (size_t)n * 256 + lane * 4);  // self-loop row (bf16)
        } else {
          int dg = cnt[s * NN + n];
          int m = min(dg, CAP);
          const ushort* lst = csrp + ((size_t)s * NN + n) * CAP;
          float a0 = 0.f, a1 = 0.f, a2 = 0.f, a3 = 0.f;
          int j = 0;
          for (; j + 8 <= m; j += 8) {   // 8 independent 512B row-gathers in flight
            int s0 = lst[j], s1 = lst[j+1], s2 = lst[j+2], s3 = lst[j+3];
            int s4 = lst[j+4], s5 = lst[j+5], s6 = lst[j+6], s7 = lst[j+7];
            ushort4 v0 = *(const ushort4*)(xb + (size_t)s0 * 256 + lane * 4);
            ushort4 v1 = *(const ushort4*)(xb + (size_t)s1 * 256 + lane * 4);
            ushort4 v2 = *(const ushort4*)(xb + (size_t)s2 * 256 + lane * 4);
            ushort4 v3 = *(const ushort4*)(xb + (size_t)s3 * 256 + lane * 4);
            ushort4 v4 = *(const ushort4*)(xb + (size_t)s4 * 256 + lane * 4);
            ushort4 v5 = *(const ushort4*)(xb + (size_t)s5 * 256 + lane * 4);
            ushort4 v6 = *(const ushort4*)(xb + (size_t)s6 * 256 + lane * 4);
            ushort4 v7 = *(const ushort4*)(xb + (size_t)s7 * 256 + lane * 4);
            a0 += ((b2f(v0.x)+b2f(v1.x))+(b2f(v2.x)+b2f(v3.x)))
                + ((b2f(v4.x)+b2f(v5.x))+(b2f(v6.x)+b2f(v7.x)));
            a1 += ((b2f(v0.y)+b2f(v1.y))+(b2f(v2.y)+b2f(v3.y)))
                + ((b2f(v4.y)+b2f(v5.y))+(b2f(v6.y)+b2f(v7.y)));
            a2 += ((b2f(v0.z)+b2f(v1.z))+(b2f(v2.z)+b2f(v3.z)))
                + ((b2f(v4.z)+b2f(v5.z))+(b2f(v6.z)+b2f(v7.z)));
            a3 += ((b2f(v0.w)+b2f(v1.w))+(b2f(v2.w)+b2f(v3.w)))
                + ((b2f(v4.w)+b2f(v5.w))+(b2f(v6.w)+b2f(v7.w)));
          }
          if (m & 4) {
            int s0 = lst[j], s1 = lst[j+1], s2 = lst[j+2], s3 = lst[j+3];
            ushort4 v0 = *(const ushort4*)(xb + (size_t)s0 * 256 + lane * 4);
            ushort4 v1 = *(const ushort4*)(xb + (size_t)s1 * 256 + lane * 4);
            ushort4 v2 = *(const ushort4*)(xb + (size_t)s2 * 256 + lane * 4);
            ushort4 v3 = *(const ushort4*)(xb + (size_t)s3 * 256 + lane * 4);
            a0 += (b2f(v0.x)+b2f(v1.x))+(b2f(v2.x)+b2f(v3.x));
            a1 += (b2f(v0.y)+b2f(v1.y))+(b2f(v2.y)+b2f(v3.y));
            a2 += (b2f(v0.z)+b2f(v1.z))+(b2f(v2.z)+b2f(v3.z));
            a3 += (b2f(v0.w)+b2f(v1.w))+(b2f(v2.w)+b2f(v3.w));
            j += 4;
          }
          if (m & 2) {
            int s0 = lst[j], s1 = lst[j+1];
            ushort4 v0 = *(const ushort4*)(xb + (size_t)s0 * 256 + lane * 4);
            ushort4 v1 = *(const ushort4*)(xb + (size_t)s1 * 256 + lane * 4);
            a0 += b2f(v0.x)+b2f(v1.x); a1 += b2f(v0.y)+b2f(v1.y);
            a2 += b2f(v0.z)+b2f(v1.z); a3 += b2f(v0.w)+b2f(v1.w);
            j += 2;
          }
          if (m & 1) {
            ushort4 v0 = *(const ushort4*)(xb + (size_t)lst[j] * 256 + lane * 4);
            a0 += b2f(v0.x); a1 += b2f(v0.y); a2 += b2f(v0.z); a3 += b2f(v0.w);
          }
          float inv = 1.f / (float)max(dg, 1);
          o[0] = ((unsigned)f2b(a0 * inv)) | (((unsigned)f2b(a1 * inv)) << 16);
          o[1] = ((unsigned)f2b(a2 * inv)) | (((unsigned)f2b(a3 * inv)) << 16);
        }
      }
      *(uint2v*)((char*)As + wbyte) = o;
    }
    __syncthreads();  // As ready for all waves

    // ---- compute phase: 4 kt-steps ----
    const ushort* W = wb + (size_t)s * 65536;
    #pragma unroll 1
    for (int kt = 0; kt < 4; ++kt) {
      #pragma unroll
      for (int it = 0; it < 4; ++it) {
        int c = it * 512 + t;            // 0..2047
        int row = c >> 3, sg = c & 7;
        int sgg = sg ^ (row & 7);
        const ushort* gb = W + (size_t)row * 256 + kt * 64 + sgg * 8;
        __builtin_amdgcn_global_load_lds(
            (const __attribute__((address_space(1))) unsigned int*)gb,
            (__attribute__((address_space(3))) unsigned int*)(Bs + c * 8), 16, 0, 0);
      }
      __syncthreads();  // drains vmcnt: Bs ready
      #pragma unroll
      for (int kk = 0; kk < 2; ++kk) {
        int ko = kk * 32 + (lane >> 4) * 8;       // ushort offset within BK=64
        int kbB = ko * 2;                         // Bs byte offset
        int kbA = (kt * 64 + ko) * 2;             // As byte offset within 512B row
        short8v a_frag[2], b_frag[4];
        #pragma unroll
        for (int mi = 0; mi < 2; ++mi) {
          int row = wm * 32 + mi * 16 + (lane & 15);
          int ba = row * 512 + (kbA ^ ((row & 7) << 4));
          a_frag[mi] = *(const short8v*)((const char*)As + ba);
        }
        #pragma unroll
        for (int ni = 0; ni < 4; ++ni) {
          int row = wn * 64 + ni * 16 + (lane & 15);
          int bb = row * 128 + (kbB ^ ((row & 7) << 4));
          b_frag[ni] = *(const short8v*)((const char*)Bs + bb);
        }
        #pragma unroll
        for (int mi = 0; mi < 2; ++mi)
          #pragma unroll
          for (int ni = 0; ni < 4; ++ni)
            acc[mi][ni] = __builtin_amdgcn_mfma_f32_16x16x32_bf16(
                a_frag[mi], b_frag[ni], acc[mi][ni], 0, 0, 0);
      }
      __syncthreads();  // Bs consumed (and, at kt=3, As consumed) before overwrite
    }
  }

  // ---- epilogue: bias + relu, nt stores ----
  #pragma unroll
  for (int mi = 0; mi < 2; ++mi) {
    int rbase = nb + wm * 32 + mi * 16 + ((lane >> 4) << 2);
    #pragma unroll
    for (int ni = 0; ni < 4; ++ni) {
      int col = wn * 64 + ni * 16 + (lane & 15);
      float bv = bias[col];
      #pragma unroll
      for (int rg = 0; rg < 4; ++rg) {
        int gm = rbase + rg;
        if (gm < NN) {
          float v = fmaxf(acc[mi][ni][rg] + bv, 0.f);
          __builtin_nontemporal_store(v, &out[(size_t)gm * 256 + col]);
        }
      }
    }
  }
}

// ---------------- host ----------------

extern "C" void kernel_launch(void* const* d_in, const int* in_sizes, int n_in,
                              void* d_out, int out_size, void* d_ws, size_t ws_size,
                              hipStream_t stream) {
  const float* x = (const float*)d_in[0];
  const float* w = (const float*)d_in[1];
  const float* bias = (const float*)d_in[2];
  const float* lw = (const float*)d_in[3];
  const int* src = (const int*)d_in[4];
  const int* dst = (const int*)d_in[5];
  float* out = (float*)d_out;

  char* ws = (char*)d_ws;
  size_t off = 0;
  auto carve = [&](size_t bytes) {
    size_t o = off;
    off = (off + bytes + 255) & ~(size_t)255;
    return o;
  };
  int* cnt = (int*)(ws + carve((size_t)NR * NN * 4));
  ushort* csrp = (ushort*)(ws + carve((size_t)NR * NN * CAP * 2));
  ushort* wb = (ushort*)(ws + carve((size_t)9 * 65536 * 2));
  ushort* xb = (ushort*)(ws + carve((size_t)NPAD * 256 * 2));

  (void)hipMemsetAsync(cnt, 0, (size_t)NR * NN * 4, stream);
  k_prep<<<XBLK + TBLK + 8 * CPB * NR, 256, 0, stream>>>(x, w, lw, xb, wb,
                                                         src, dst, cnt, csrp);
  k_fused<<<NPAD / 64, 512, 0, stream>>>(xb, wb, csrp, cnt, bias, out);

  (void)in_sizes; (void)n_in; (void)out_size; (void)ws_size;
}

// Round 14
// 528.579 us; speedup vs baseline: 1.0448x; 1.0448x over previous
//
#include <hip/hip_runtime.h>
#include <hip/hip_bf16.h>

#define NN 50000
#define NPAD 50048   // 782 * 64
#define NR 8
#define NE 400000
#define CAP 32       // bucket capacity: 32 x 2B = one 64B line per (rel,node)
#define CHUNK 2048
#define CPB 196      // ceil(NE / CHUNK)
#define NRANGE 6250  // NN / 8 node-range per XCD slice
#define XBLK 12500   // NN*64/256 conversion blocks for x
#define TBLK 144     // 9 segs * 16 (64x64) transpose tiles for W

typedef __attribute__((ext_vector_type(8))) short short8v;
typedef __attribute__((ext_vector_type(4))) float f32x4;
typedef __attribute__((ext_vector_type(2))) unsigned int uint2v;

static __device__ __forceinline__ ushort f2b(float f) {
  union { float f; unsigned u; } v; v.f = f;
  unsigned u = v.u;
  unsigned r = (u + 0x7fffu + ((u >> 16) & 1u)) >> 16;
  return (ushort)r;
}
static __device__ __forceinline__ float b2f(ushort u) {
  union { unsigned u; float f; } v; v.u = ((unsigned)u) << 16;
  return v.f;
}

// ---------------- merged prep: x->bf16, W->bf16 [seg][n][k] (LDS transpose), CSR fill ----------------

__global__ __launch_bounds__(256) void k_prep(const float* __restrict__ x,
                                              const float* __restrict__ w,
                                              const float* __restrict__ lw,
                                              ushort* __restrict__ xb,
                                              ushort* __restrict__ wb,
                                              const int* __restrict__ src,
                                              const int* __restrict__ dst,
                                              int* __restrict__ cnt,
                                              ushort* __restrict__ csrp) {
  __shared__ ushort tile[64][66];  // pitch 66: transposed read stride 33 dwords (conflict-free)
  int b = blockIdx.x;
  if (b < XBLK) {
    int i = b * 256 + threadIdx.x;  // one float4 per thread
    float4 v = ((const float4*)x)[i];
    ushort4 o;
    o.x = f2b(v.x); o.y = f2b(v.y); o.z = f2b(v.z); o.w = f2b(v.w);
    ((ushort4*)xb)[i] = o;
    return;
  }
  if (b < XBLK + TBLK) {
    // W transpose: 64x64 tile, coalesced loads, coalesced stores.
    int tb = b - XBLK;
    int s = tb >> 4, t16 = tb & 15;
    int kt = (t16 >> 2) * 64, nt2 = (t16 & 3) * 64;
    const float* srcw = (s < 8) ? (w + (size_t)s * 65536) : lw;
    int t = threadIdx.x;
    #pragma unroll
    for (int i = 0; i < 16; ++i) {
      int flat = i * 256 + t;
      int kk = flat >> 6, nn = flat & 63;
      tile[kk][nn] = f2b(srcw[(size_t)(kt + kk) * 256 + nt2 + nn]);
    }
    __syncthreads();
    #pragma unroll
    for (int i = 0; i < 16; ++i) {
      int flat = i * 256 + t;
      int nn2 = flat >> 6, kk2 = flat & 63;
      wb[(size_t)s * 65536 + (size_t)(nt2 + nn2) * 256 + kt + kk2] = tile[kk2][nn2];
    }
    return;
  }
  // CSR fill: xcd slice by GLOBAL blockIdx parity (8 consecutive bids per chunk cover all 8)
  int xcd = b & 7;
  int rc = (b - XBLK - TBLK) >> 3;
  int r = rc / CPB;
  int c = rc - r * CPB;
  int nlo = xcd * NRANGE, nhi = nlo + NRANGE;
  const int* dr = dst + (size_t)r * NE;
  const int* sr = src + (size_t)r * NE;
  int e0 = c * CHUNK + threadIdx.x * 4;
  #pragma unroll
  for (int u = 0; u < CHUNK / 1024; ++u) {
    int e = e0 + u * 1024;
    if (e + 3 < NE) {
      int4 d4 = *(const int4*)(dr + e);
      int4 s4 = *(const int4*)(sr + e);
      #pragma unroll
      for (int k = 0; k < 4; ++k) {
        int d = (k == 0) ? d4.x : (k == 1) ? d4.y : (k == 2) ? d4.z : d4.w;
        int s = (k == 0) ? s4.x : (k == 1) ? s4.y : (k == 2) ? s4.z : s4.w;
        if (d >= nlo && d < nhi) {
          int slot = atomicAdd(&cnt[r * NN + d], 1);
          if (slot < CAP)
            csrp[((size_t)r * NN + d) * CAP + slot] = (ushort)s;
        }
      }
    } else {
      for (int k = 0; k < 4; ++k) {
        int e2 = e + k;
        if (e2 < NE) {
          int d = dr[e2];
          if (d >= nlo && d < nhi) {
            int slot = atomicAdd(&cnt[r * NN + d], 1);
            if (slot < CAP)
              csrp[((size_t)r * NN + d) * CAP + slot] = (ushort)sr[e2];
          }
        }
      }
    }
  }
}

// ---------------- aggregation: one wave per (node, rel), unroll-4, nt stores ----------------

__global__ __launch_bounds__(256) void k_agg(const ushort* __restrict__ xb,
                                             const ushort* __restrict__ csrp,
                                             const int* __restrict__ cnt,
                                             ushort* __restrict__ xa,
                                             long strideR, int r0) {
  int wid = threadIdx.x >> 6, lane = threadIdx.x & 63;
  int n = blockIdx.x * 4 + wid;
  int r = r0 + blockIdx.y;
  if (n >= NN) return;
  int dg = cnt[r * NN + n];
  int m = min(dg, CAP);
  const ushort* lst = csrp + ((size_t)r * NN + n) * CAP;
  float a0 = 0.f, a1 = 0.f, a2 = 0.f, a3 = 0.f;
  int j = 0;
  for (; j + 3 < m; j += 4) {
    int s0 = lst[j], s1 = lst[j + 1], s2 = lst[j + 2], s3 = lst[j + 3];
    ushort4 v0 = *(const ushort4*)(xb + (size_t)s0 * 256 + lane * 4);
    ushort4 v1 = *(const ushort4*)(xb + (size_t)s1 * 256 + lane * 4);
    ushort4 v2 = *(const ushort4*)(xb + (size_t)s2 * 256 + lane * 4);
    ushort4 v3 = *(const ushort4*)(xb + (size_t)s3 * 256 + lane * 4);
    a0 += (b2f(v0.x) + b2f(v1.x)) + (b2f(v2.x) + b2f(v3.x));
    a1 += (b2f(v0.y) + b2f(v1.y)) + (b2f(v2.y) + b2f(v3.y));
    a2 += (b2f(v0.z) + b2f(v1.z)) + (b2f(v2.z) + b2f(v3.z));
    a3 += (b2f(v0.w) + b2f(v1.w)) + (b2f(v2.w) + b2f(v3.w));
  }
  for (; j < m; ++j) {
    ushort4 v0 = *(const ushort4*)(xb + (size_t)lst[j] * 256 + lane * 4);
    a0 += b2f(v0.x); a1 += b2f(v0.y); a2 += b2f(v0.z); a3 += b2f(v0.w);
  }
  float inv = 1.f / (float)max(dg, 1);
  unsigned w0 = ((unsigned)f2b(a0 * inv)) | (((unsigned)f2b(a1 * inv)) << 16);
  unsigned w1 = ((unsigned)f2b(a2 * inv)) | (((unsigned)f2b(a3 * inv)) << 16);
  uint2v o; o[0] = w0; o[1] = w1;
  __builtin_nontemporal_store(o, (uint2v*)(xa + (size_t)(r - r0) * strideR +
                                           (size_t)n * 256 + lane * 4));
}

// ---------------- GEMM: BM=64 x BN=256, 512 threads (8 waves 2x4), counted-vmcnt pipeline ----------
// Grid = 782 blocks = 3.05/CU (balanced); LDS 48KB (As dbuf 2x8KB + Bs 32KB) -> 3 blocks/CU.
// Per step: barrier; STAGE_B(cur) [4 chunks/thr]; STAGE_A(next->buf^1) [1 chunk/thr];
// vmcnt(1) retires A_cur+B_cur (FIFO), leaves only next-A in flight; barrier; 16 MFMA.
// Both-sides XOR swizzle (r8-verified) on A and B.

#define BK 64

__global__ __launch_bounds__(512, 6) void k_gemm(
    const ushort* __restrict__ xa, long strideR, int nseg,
    const ushort* __restrict__ xb8, const ushort* __restrict__ wb, int wseg0,
    const float* __restrict__ bias, float* __restrict__ out, int first, int final_) {
  __shared__ ushort As[2][64 * BK];   // 2 x 8 KB
  __shared__ ushort Bs[256 * BK];     // 32 KB
  int t = threadIdx.x;
  int lane = t & 63, wid = t >> 6;
  int wm = wid >> 2, wn = wid & 3;    // 2 x 4
  int i0 = blockIdx.x * 64;
  const int NT = nseg * 4;

  f32x4 acc[2][4];
  #pragma unroll
  for (int a = 0; a < 2; ++a)
    #pragma unroll
    for (int b = 0; b < 4; ++b) acc[a][b] = (f32x4){0.f, 0.f, 0.f, 0.f};

#define STAGE_A(stp, buf) do {                                                  \
    int s_ = (stp) >> 2; int kt_ = ((stp) & 3) * 64;                            \
    const ushort* A_ = (wseg0 + s_ < 8) ? (xa + (size_t)s_ * strideR) : xb8;    \
    int c = t; int row = c >> 3, sg = c & 7;                                    \
    int sgg = sg ^ (row & 7);                                                   \
    const ushort* ga = A_ + (size_t)(i0 + row) * 256 + kt_ + sgg * 8;           \
    __builtin_amdgcn_global_load_lds(                                           \
        (const __attribute__((address_space(1))) unsigned int*)ga,              \
        (__attribute__((address_space(3))) unsigned int*)(As[buf] + c * 8),     \
        16, 0, 0);                                                              \
  } while (0)

#define STAGE_B(stp) do {                                                       \
    int s_ = (stp) >> 2; int kt_ = ((stp) & 3) * 64;                            \
    const ushort* W_ = wb + (size_t)(wseg0 + s_) * 65536;                       \
    _Pragma("unroll")                                                           \
    for (int it = 0; it < 4; ++it) {                                            \
      int c = it * 512 + t; int row = c >> 3, sg = c & 7;                       \
      int sgg = sg ^ (row & 7);                                                 \
      const ushort* gb = W_ + (size_t)row * 256 + kt_ + sgg * 8;                \
      __builtin_amdgcn_global_load_lds(                                         \
          (const __attribute__((address_space(1))) unsigned int*)gb,            \
          (__attribute__((address_space(3))) unsigned int*)(Bs + c * 8),        \
          16, 0, 0);                                                            \
    } } while (0)

  STAGE_A(0, 0);  // prologue
  int cur = 0;
  #pragma unroll 1
  for (int st = 0; st < NT; ++st) {
    __builtin_amdgcn_s_barrier();  // all waves done reading Bs / As[cur^1]
    STAGE_B(st);
    if (st + 1 < NT) {
      STAGE_A(st + 1, cur ^ 1);
      asm volatile("s_waitcnt vmcnt(1)" ::: "memory");  // A(cur)+B(cur) retired
    } else {
      asm volatile("s_waitcnt vmcnt(0)" ::: "memory");
    }
    __builtin_amdgcn_sched_barrier(0);
    __builtin_amdgcn_s_barrier();  // tiles visible to all waves
    __builtin_amdgcn_sched_barrier(0);
    const ushort* Ac = As[cur];
    #pragma unroll
    for (int kk = 0; kk < 2; ++kk) {
      int ko = kk * 32 + (lane >> 4) * 8;   // ushort offset within row
      int kb = ko * 2;                      // byte offset (16B-aligned)
      short8v a_frag[2], b_frag[4];
      #pragma unroll
      for (int mi = 0; mi < 2; ++mi) {
        int row = wm * 32 + mi * 16 + (lane & 15);
        int ba = row * 128 + (kb ^ ((row & 7) << 4));
        a_frag[mi] = *(const short8v*)((const char*)Ac + ba);
      }
      #pragma unroll
      for (int ni = 0; ni < 4; ++ni) {
        int row = wn * 64 + ni * 16 + (lane & 15);
        int ba = row * 128 + (kb ^ ((row & 7) << 4));
        b_frag[ni] = *(const short8v*)((const char*)Bs + ba);
      }
      #pragma unroll
      for (int mi = 0; mi < 2; ++mi)
        #pragma unroll
        for (int ni = 0; ni < 4; ++ni)
          acc[mi][ni] = __builtin_amdgcn_mfma_f32_16x16x32_bf16(
              a_frag[mi], b_frag[ni], acc[mi][ni], 0, 0, 0);
    }
    cur ^= 1;
  }
#undef STAGE_A
#undef STAGE_B

  // epilogue: C elem (col = lane&15, row = (lane>>4)*4 + reg)
  #pragma unroll
  for (int mi = 0; mi < 2; ++mi) {
    int rbase = i0 + wm * 32 + mi * 16 + ((lane >> 4) << 2);
    #pragma unroll
    for (int ni = 0; ni < 4; ++ni) {
      int col = wn * 64 + ni * 16 + (lane & 15);
      float bv = final_ ? bias[col] : 0.f;
      #pragma unroll
      for (int rg = 0; rg < 4; ++rg) {
        int gm = rbase + rg;
        if (gm < NN) {
          size_t o = (size_t)gm * 256 + col;
          float v = acc[mi][ni][rg];
          if (!first) v += out[o];
          if (final_) v = fmaxf(v + bv, 0.f);
          out[o] = v;
        }
      }
    }
  }
}

// ---------------- host ----------------

extern "C" void kernel_launch(void* const* d_in, const int* in_sizes, int n_in,
                              void* d_out, int out_size, void* d_ws, size_t ws_size,
                              hipStream_t stream) {
  const float* x = (const float*)d_in[0];
  const float* w = (const float*)d_in[1];
  const float* bias = (const float*)d_in[2];
  const float* lw = (const float*)d_in[3];
  const int* src = (const int*)d_in[4];
  const int* dst = (const int*)d_in[5];
  float* out = (float*)d_out;

  char* ws = (char*)d_ws;
  size_t off = 0;
  auto carve = [&](size_t bytes) {
    size_t o = off;
    off = (off + bytes + 255) & ~(size_t)255;
    return o;
  };
  int* cnt = (int*)(ws + carve((size_t)NR * NN * 4));
  ushort* csrp = (ushort*)(ws + carve((size_t)NR * NN * CAP * 2));
  ushort* wb = (ushort*)(ws + carve((size_t)9 * 65536 * 2));
  ushort* xb = (ushort*)(ws + carve((size_t)NPAD * 256 * 2));
  size_t base_bytes = off;
  ushort* xa = (ushort*)(ws + off);
  const size_t segb = (size_t)NPAD * 256 * 2;
  long strideR = (long)NPAD * 256;

  (void)hipMemsetAsync(cnt, 0, (size_t)NR * NN * 4, stream);
  k_prep<<<XBLK + TBLK + 8 * CPB * NR, 256, 0, stream>>>(x, w, lw, xb, wb,
                                                         src, dst, cnt, csrp);

  dim3 gemm_grid(NPAD / 64);
  if (ws_size >= base_bytes + 8 * segb) {
    // Tier A: all 8 aggregated segments at once, single GEMM over 9 segs.
    k_agg<<<dim3((NN + 3) / 4, 8), 256, 0, stream>>>(xb, csrp, cnt, xa, strideR, 0);
    k_gemm<<<gemm_grid, 512, 0, stream>>>(xa, strideR, 9, xb, wb, 0, bias, out, 1, 1);
  } else if (ws_size >= base_bytes + 4 * segb) {
    // Tier B: two 4-segment passes.
    k_agg<<<dim3((NN + 3) / 4, 4), 256, 0, stream>>>(xb, csrp, cnt, xa, strideR, 0);
    k_gemm<<<gemm_grid, 512, 0, stream>>>(xa, strideR, 4, xb, wb, 0, bias, out, 1, 0);
    k_agg<<<dim3((NN + 3) / 4, 4), 256, 0, stream>>>(xb, csrp, cnt, xa, strideR, 4);
    k_gemm<<<gemm_grid, 512, 0, stream>>>(xa, strideR, 5, xb, wb, 4, bias, out, 0, 1);
  } else {
    // Tier C: one relation at a time.
    for (int r = 0; r < 8; ++r) {
      k_agg<<<dim3((NN + 3) / 4, 1), 256, 0, stream>>>(xb, csrp, cnt, xa, strideR, r);
      k_gemm<<<gemm_grid, 512, 0, stream>>>(xa, strideR, 1, xb, wb, r, bias, out,
                                            (r == 0) ? 1 : 0, 0);
    }
    k_gemm<<<gemm_grid, 512, 0, stream>>>(xa, strideR, 1, xb, wb, 8, bias, out, 0, 1);
  }
  (void)in_sizes; (void)n_in; (void)out_size;
}

// Round 15
// 492.816 us; speedup vs baseline: 1.1207x; 1.0726x over previous
//
#include <hip/hip_runtime.h>
#include <hip/hip_bf16.h>

#define NN 50000
#define NPAD 50048   // 391 * 128
#define NR 8
#define NE 400000
#define CAP 32       // bucket capacity: 32 x 2B = one 64B line per (rel,node)
#define CHUNK 2048
#define CPB 196      // ceil(NE / CHUNK)
#define NRANGE 6250  // NN / 8 node-range per XCD slice
#define XBLK 12500   // NN*64/256 conversion blocks for x
#define TBLK 144     // 9 segs * 16 (64x64) transpose tiles for W

typedef __attribute__((ext_vector_type(8))) short short8v;
typedef __attribute__((ext_vector_type(4))) float f32x4;
typedef __attribute__((ext_vector_type(2))) unsigned int uint2v;

static __device__ __forceinline__ ushort f2b(float f) {
  union { float f; unsigned u; } v; v.f = f;
  unsigned u = v.u;
  unsigned r = (u + 0x7fffu + ((u >> 16) & 1u)) >> 16;
  return (ushort)r;
}
static __device__ __forceinline__ float b2f(ushort u) {
  union { unsigned u; float f; } v; v.u = ((unsigned)u) << 16;
  return v.f;
}

// Blocked A layout (xbc, xa, all GEMM A-operands):
//   elem(n, col) at  base[ ((col>>5)*NPAD + n)*32 + (col&31) ]
// 64B per (node, 32-col chunk) -> chunk slice = 3.2MB (L2-resident per XCD).

// ---------------- merged prep: x->bf16 blocked, W->bf16 [seg][n][k], CSR fill ----------------

__global__ __launch_bounds__(256) void k_prep(const float* __restrict__ x,
                                              const float* __restrict__ w,
                                              const float* __restrict__ lw,
                                              ushort* __restrict__ xbc,
                                              ushort* __restrict__ wb,
                                              const int* __restrict__ src,
                                              const int* __restrict__ dst,
                                              int* __restrict__ cnt,
                                              ushort* __restrict__ csrp) {
  __shared__ ushort tile[64][66];  // pitch 66: transposed read stride 33 dwords (conflict-free)
  int b = blockIdx.x;
  if (b < XBLK) {
    int i = b * 256 + threadIdx.x;  // one float4 per thread
    int n = i >> 6, q = i & 63;     // cols 4q..4q+3
    float4 v = ((const float4*)x)[i];
    ushort4 o;
    o.x = f2b(v.x); o.y = f2b(v.y); o.z = f2b(v.z); o.w = f2b(v.w);
    *(ushort4*)(xbc + ((size_t)(q >> 3) * NPAD + n) * 32 + (q & 7) * 4) = o;
    return;
  }
  if (b < XBLK + TBLK) {
    // W transpose: 64x64 tile, coalesced loads, coalesced stores.
    int tb = b - XBLK;
    int s = tb >> 4, t16 = tb & 15;
    int kt = (t16 >> 2) * 64, nt2 = (t16 & 3) * 64;
    const float* srcw = (s < 8) ? (w + (size_t)s * 65536) : lw;
    int t = threadIdx.x;
    #pragma unroll
    for (int i = 0; i < 16; ++i) {
      int flat = i * 256 + t;
      int kk = flat >> 6, nn = flat & 63;
      tile[kk][nn] = f2b(srcw[(size_t)(kt + kk) * 256 + nt2 + nn]);
    }
    __syncthreads();
    #pragma unroll
    for (int i = 0; i < 16; ++i) {
      int flat = i * 256 + t;
      int nn2 = flat >> 6, kk2 = flat & 63;
      wb[(size_t)s * 65536 + (size_t)(nt2 + nn2) * 256 + kt + kk2] = tile[kk2][nn2];
    }
    return;
  }
  // CSR fill: xcd slice by GLOBAL blockIdx parity (8 consecutive bids per chunk cover all 8)
  int xcd = b & 7;
  int rc = (b - XBLK - TBLK) >> 3;
  int r = rc / CPB;
  int c = rc - r * CPB;
  int nlo = xcd * NRANGE, nhi = nlo + NRANGE;
  const int* dr = dst + (size_t)r * NE;
  const int* sr = src + (size_t)r * NE;
  int e0 = c * CHUNK + threadIdx.x * 4;
  #pragma unroll
  for (int u = 0; u < CHUNK / 1024; ++u) {
    int e = e0 + u * 1024;
    if (e + 3 < NE) {
      int4 d4 = *(const int4*)(dr + e);
      int4 s4 = *(const int4*)(sr + e);
      #pragma unroll
      for (int k = 0; k < 4; ++k) {
        int d = (k == 0) ? d4.x : (k == 1) ? d4.y : (k == 2) ? d4.z : d4.w;
        int s = (k == 0) ? s4.x : (k == 1) ? s4.y : (k == 2) ? s4.z : s4.w;
        if (d >= nlo && d < nhi) {
          int slot = atomicAdd(&cnt[r * NN + d], 1);
          if (slot < CAP)
            csrp[((size_t)r * NN + d) * CAP + slot] = (ushort)s;
        }
      }
    } else {
      for (int k = 0; k < 4; ++k) {
        int e2 = e + k;
        if (e2 < NE) {
          int d = dr[e2];
          if (d >= nlo && d < nhi) {
            int slot = atomicAdd(&cnt[r * NN + d], 1);
            if (slot < CAP)
              csrp[((size_t)r * NN + d) * CAP + slot] = (ushort)sr[e2];
          }
        }
      }
    }
  }
}

// ---------------- chunked aggregation: 8-lane group per node, chunk = slowest dim ----------------
// grid (ceil(NN/32), nrel, 8). Each block: 32 nodes x one (rel, chunk). The 3.2MB xbc
// chunk slice is L2-resident while all concurrent blocks gather from it. Buckets are
// one 64B line each (broadcast loads within the group), unroll-4 independent gathers.

__global__ __launch_bounds__(256) void k_aggc(const ushort* __restrict__ xbc,
                                              const ushort* __restrict__ csrp,
                                              const int* __restrict__ cnt,
                                              ushort* __restrict__ xa,
                                              long strideR, int r0) {
  int t = threadIdx.x;
  int gl = t & 7;
  int n = blockIdx.x * 32 + (t >> 3);
  int r = r0 + blockIdx.y;
  int c = blockIdx.z;
  if (n >= NN) return;
  int dg = cnt[r * NN + n];
  int m = min(dg, CAP);
  const ushort* lst = csrp + ((size_t)r * NN + n) * CAP;
  const ushort* xc = xbc + (size_t)c * NPAD * 32;
  float a0 = 0.f, a1 = 0.f, a2 = 0.f, a3 = 0.f;
  int j = 0;
  for (; j + 3 < m; j += 4) {
    int s0 = lst[j], s1 = lst[j + 1], s2 = lst[j + 2], s3 = lst[j + 3];
    ushort4 v0 = *(const ushort4*)(xc + (size_t)s0 * 32 + gl * 4);
    ushort4 v1 = *(const ushort4*)(xc + (size_t)s1 * 32 + gl * 4);
    ushort4 v2 = *(const ushort4*)(xc + (size_t)s2 * 32 + gl * 4);
    ushort4 v3 = *(const ushort4*)(xc + (size_t)s3 * 32 + gl * 4);
    a0 += (b2f(v0.x) + b2f(v1.x)) + (b2f(v2.x) + b2f(v3.x));
    a1 += (b2f(v0.y) + b2f(v1.y)) + (b2f(v2.y) + b2f(v3.y));
    a2 += (b2f(v0.z) + b2f(v1.z)) + (b2f(v2.z) + b2f(v3.z));
    a3 += (b2f(v0.w) + b2f(v1.w)) + (b2f(v2.w) + b2f(v3.w));
  }
  for (; j < m; ++j) {
    ushort4 v0 = *(const ushort4*)(xc + (size_t)lst[j] * 32 + gl * 4);
    a0 += b2f(v0.x); a1 += b2f(v0.y); a2 += b2f(v0.z); a3 += b2f(v0.w);
  }
  float inv = 1.f / (float)max(dg, 1);
  unsigned w0 = ((unsigned)f2b(a0 * inv)) | (((unsigned)f2b(a1 * inv)) << 16);
  unsigned w1 = ((unsigned)f2b(a2 * inv)) | (((unsigned)f2b(a3 * inv)) << 16);
  uint2v o; o[0] = w0; o[1] = w1;
  __builtin_nontemporal_store(o, (uint2v*)(xa + (size_t)(r - r0) * strideR +
                                           ((size_t)c * NPAD + n) * 32 + gl * 4));
}

// ---------------- GEMM (r12 structure): BM=128 x BN=256, counted-vmcnt pipeline ----------------
// A operands in blocked layout; LDS content/mapping identical to r12 (only global addr calc
// changed). A dbuf 2x16KB + Bs 32KB = 64KB, 2 blocks/CU. Both-sides XOR swizzle (r8-verified).

#define BK 64

__global__ __launch_bounds__(512, 4) void k_gemm(
    const ushort* __restrict__ xa, long strideR, int nseg,
    const ushort* __restrict__ xb8, const ushort* __restrict__ wb, int wseg0,
    const float* __restrict__ bias, float* __restrict__ out, int first, int final_) {
  __shared__ ushort As[2][128 * BK];  // 2 x 16 KB
  __shared__ ushort Bs[256 * BK];     // 32 KB
  int t = threadIdx.x;
  int lane = t & 63, wid = t >> 6;
  int wm = wid >> 2, wn = wid & 3;
  int i0 = blockIdx.x * 128;
  const int NT = nseg * 4;

  f32x4 acc[4][4];
  #pragma unroll
  for (int a = 0; a < 4; ++a)
    #pragma unroll
    for (int b = 0; b < 4; ++b) acc[a][b] = (f32x4){0.f, 0.f, 0.f, 0.f};

#define STAGE_A(stp, buf) do {                                                  \
    int s_ = (stp) >> 2; int kt_ = ((stp) & 3) * 64;                            \
    const ushort* A_ = (wseg0 + s_ < 8) ? (xa + (size_t)s_ * strideR) : xb8;    \
    _Pragma("unroll")                                                           \
    for (int it = 0; it < 2; ++it) {                                            \
      int c = it * 512 + t; int row = c >> 3, sg = c & 7;                       \
      int sgg = sg ^ (row & 7);                                                 \
      int col = kt_ + sgg * 8;                                                  \
      const ushort* ga = A_ + ((size_t)(col >> 5) * NPAD + (i0 + row)) * 32     \
                            + (col & 31);                                       \
      __builtin_amdgcn_global_load_lds(                                         \
          (const __attribute__((address_space(1))) unsigned int*)ga,            \
          (__attribute__((address_space(3))) unsigned int*)(As[buf] + c * 8),   \
          16, 0, 0);                                                            \
    } } while (0)

#define STAGE_B(stp) do {                                                       \
    int s_ = (stp) >> 2; int kt_ = ((stp) & 3) * 64;                            \
    const ushort* W_ = wb + (size_t)(wseg0 + s_) * 65536;                       \
    _Pragma("unroll")                                                           \
    for (int it = 0; it < 4; ++it) {                                            \
      int c = it * 512 + t; int row = c >> 3, sg = c & 7;                       \
      int sgg = sg ^ (row & 7);                                                 \
      const ushort* gb = W_ + (size_t)row * 256 + kt_ + sgg * 8;                \
      __builtin_amdgcn_global_load_lds(                                         \
          (const __attribute__((address_space(1))) unsigned int*)gb,            \
          (__attribute__((address_space(3))) unsigned int*)(Bs + c * 8),        \
          16, 0, 0);                                                            \
    } } while (0)

  STAGE_A(0, 0);  // prologue
  int cur = 0;
  #pragma unroll 1
  for (int st = 0; st < NT; ++st) {
    __builtin_amdgcn_s_barrier();  // all waves done reading Bs / As[cur^1]
    STAGE_B(st);
    if (st + 1 < NT) {
      STAGE_A(st + 1, cur ^ 1);
      asm volatile("s_waitcnt vmcnt(2)" ::: "memory");  // A(cur)+B(cur) retired
    } else {
      asm volatile("s_waitcnt vmcnt(0)" ::: "memory");
    }
    __builtin_amdgcn_sched_barrier(0);
    __builtin_amdgcn_s_barrier();  // tiles visible to all waves
    __builtin_amdgcn_sched_barrier(0);
    const ushort* Ac = As[cur];
    #pragma unroll
    for (int kk = 0; kk < 2; ++kk) {
      int ko = kk * 32 + (lane >> 4) * 8;   // ushort offset within row
      int kb = ko * 2;                      // byte offset (16B-aligned)
      short8v a_frag[4], b_frag[4];
      #pragma unroll
      for (int mi = 0; mi < 4; ++mi) {
        int row = wm * 64 + mi * 16 + (lane & 15);
        int ba = row * 128 + (kb ^ ((row & 7) << 4));
        a_frag[mi] = *(const short8v*)((const char*)Ac + ba);
      }
      #pragma unroll
      for (int ni = 0; ni < 4; ++ni) {
        int row = wn * 64 + ni * 16 + (lane & 15);
        int ba = row * 128 + (kb ^ ((row & 7) << 4));
        b_frag[ni] = *(const short8v*)((const char*)Bs + ba);
      }
      #pragma unroll
      for (int mi = 0; mi < 4; ++mi)
        #pragma unroll
        for (int ni = 0; ni < 4; ++ni)
          acc[mi][ni] = __builtin_amdgcn_mfma_f32_16x16x32_bf16(
              a_frag[mi], b_frag[ni], acc[mi][ni], 0, 0, 0);
    }
    cur ^= 1;
  }
#undef STAGE_A
#undef STAGE_B

  // epilogue: C elem (col = lane&15, row = (lane>>4)*4 + reg)
  #pragma unroll
  for (int mi = 0; mi < 4; ++mi) {
    int rbase = i0 + wm * 64 + mi * 16 + ((lane >> 4) << 2);
    #pragma unroll
    for (int ni = 0; ni < 4; ++ni) {
      int col = wn * 64 + ni * 16 + (lane & 15);
      float bv = final_ ? bias[col] : 0.f;
      #pragma unroll
      for (int rg = 0; rg < 4; ++rg) {
        int gm = rbase + rg;
        if (gm < NN) {
          size_t o = (size_t)gm * 256 + col;
          float v = acc[mi][ni][rg];
          if (!first) v += out[o];
          if (final_) v = fmaxf(v + bv, 0.f);
          out[o] = v;
        }
      }
    }
  }
}

// ---------------- host ----------------

extern "C" void kernel_launch(void* const* d_in, const int* in_sizes, int n_in,
                              void* d_out, int out_size, void* d_ws, size_t ws_size,
                              hipStream_t stream) {
  const float* x = (const float*)d_in[0];
  const float* w = (const float*)d_in[1];
  const float* bias = (const float*)d_in[2];
  const float* lw = (const float*)d_in[3];
  const int* src = (const int*)d_in[4];
  const int* dst = (const int*)d_in[5];
  float* out = (float*)d_out;

  char* ws = (char*)d_ws;
  size_t off = 0;
  auto carve = [&](size_t bytes) {
    size_t o = off;
    off = (off + bytes + 255) & ~(size_t)255;
    return o;
  };
  int* cnt = (int*)(ws + carve((size_t)NR * NN * 4));
  ushort* csrp = (ushort*)(ws + carve((size_t)NR * NN * CAP * 2));
  ushort* wb = (ushort*)(ws + carve((size_t)9 * 65536 * 2));
  ushort* xbc = (ushort*)(ws + carve((size_t)NPAD * 256 * 2));
  size_t base_bytes = off;
  ushort* xa = (ushort*)(ws + off);
  const size_t segb = (size_t)NPAD * 256 * 2;
  long strideR = (long)NPAD * 256;

  (void)hipMemsetAsync(cnt, 0, (size_t)NR * NN * 4, stream);
  k_prep<<<XBLK + TBLK + 8 * CPB * NR, 256, 0, stream>>>(x, w, lw, xbc, wb,
                                                         src, dst, cnt, csrp);

  dim3 gemm_grid(NPAD / 128);
  dim3 agg_grid((NN + 31) / 32, 8, 8);
  if (ws_size >= base_bytes + 8 * segb) {
    // Tier A: all 8 aggregated segments at once, single GEMM over 9 segs.
    k_aggc<<<agg_grid, 256, 0, stream>>>(xbc, csrp, cnt, xa, strideR, 0);
    k_gemm<<<gemm_grid, 512, 0, stream>>>(xa, strideR, 9, xbc, wb, 0, bias, out, 1, 1);
  } else if (ws_size >= base_bytes + 4 * segb) {
    // Tier B: two 4-segment passes.
    k_aggc<<<dim3((NN + 31) / 32, 4, 8), 256, 0, stream>>>(xbc, csrp, cnt, xa, strideR, 0);
    k_gemm<<<gemm_grid, 512, 0, stream>>>(xa, strideR, 4, xbc, wb, 0, bias, out, 1, 0);
    k_aggc<<<dim3((NN + 31) / 32, 4, 8), 256, 0, stream>>>(xbc, csrp, cnt, xa, strideR, 4);
    k_gemm<<<gemm_grid, 512, 0, stream>>>(xa, strideR, 5, xbc, wb, 4, bias, out, 0, 1);
  } else {
    // Tier C: one relation at a time.
    for (int r = 0; r < 8; ++r) {
      k_aggc<<<dim3((NN + 31) / 32, 1, 8), 256, 0, stream>>>(xbc, csrp, cnt, xa, strideR, r);
      k_gemm<<<gemm_grid, 512, 0, stream>>>(xa, strideR, 1, xbc, wb, r, bias, out,
                                            (r == 0) ? 1 : 0, 0);
    }
    k_gemm<<<gemm_grid, 512, 0, stream>>>(xa, strideR, 1, xbc, wb, 8, bias, out, 0, 1);
  }
  (void)in_sizes; (void)n_in; (void)out_size;
}

// Round 16
// 477.014 us; speedup vs baseline: 1.1578x; 1.0331x over previous
//
#include <hip/hip_runtime.h>
#include <hip/hip_bf16.h>

#define NN 50000
#define NPAD 50048   // 391 * 128
#define NR 8
#define NE 400000
#define CAP 32       // bucket capacity: 32 x 2B = one 64B line per (rel,node)
#define CHUNK 2048
#define CPB 196      // ceil(NE / CHUNK)
#define NRANGE 6250  // NN / 8 node-range per XCD slice
#define XBLK 12500   // NN*64/256 conversion blocks for x
#define TBLK 144     // 9 segs * 16 (64x64) transpose tiles for W

typedef __attribute__((ext_vector_type(8))) short short8v;
typedef __attribute__((ext_vector_type(4))) float f32x4;
typedef __attribute__((ext_vector_type(2))) unsigned int uint2v;

static __device__ __forceinline__ ushort f2b(float f) {
  union { float f; unsigned u; } v; v.f = f;
  unsigned u = v.u;
  unsigned r = (u + 0x7fffu + ((u >> 16) & 1u)) >> 16;
  return (ushort)r;
}
static __device__ __forceinline__ float b2f(ushort u) {
  union { unsigned u; float f; } v; v.u = ((unsigned)u) << 16;
  return v.f;
}

// ---------------- merged prep: x->bf16, W->bf16 [seg][n][k] (LDS transpose), CSR fill ----------------

__global__ __launch_bounds__(256) void k_prep(const float* __restrict__ x,
                                              const float* __restrict__ w,
                                              const float* __restrict__ lw,
                                              ushort* __restrict__ xb,
                                              ushort* __restrict__ wb,
                                              const int* __restrict__ src,
                                              const int* __restrict__ dst,
                                              int* __restrict__ cnt,
                                              ushort* __restrict__ csrp) {
  __shared__ ushort tile[64][66];  // pitch 66: transposed read stride 33 dwords (conflict-free)
  int b = blockIdx.x;
  if (b < XBLK) {
    int i = b * 256 + threadIdx.x;  // one float4 per thread
    float4 v = ((const float4*)x)[i];
    ushort4 o;
    o.x = f2b(v.x); o.y = f2b(v.y); o.z = f2b(v.z); o.w = f2b(v.w);
    ((ushort4*)xb)[i] = o;
    return;
  }
  if (b < XBLK + TBLK) {
    // W transpose: 64x64 tile, coalesced loads, coalesced stores.
    int tb = b - XBLK;
    int s = tb >> 4, t16 = tb & 15;
    int kt = (t16 >> 2) * 64, nt2 = (t16 & 3) * 64;
    const float* srcw = (s < 8) ? (w + (size_t)s * 65536) : lw;
    int t = threadIdx.x;
    #pragma unroll
    for (int i = 0; i < 16; ++i) {
      int flat = i * 256 + t;
      int kk = flat >> 6, nn = flat & 63;
      tile[kk][nn] = f2b(srcw[(size_t)(kt + kk) * 256 + nt2 + nn]);
    }
    __syncthreads();
    #pragma unroll
    for (int i = 0; i < 16; ++i) {
      int flat = i * 256 + t;
      int nn2 = flat >> 6, kk2 = flat & 63;
      wb[(size_t)s * 65536 + (size_t)(nt2 + nn2) * 256 + kt + kk2] = tile[kk2][nn2];
    }
    return;
  }
  // CSR fill: xcd slice by GLOBAL blockIdx parity (8 consecutive bids per chunk cover all 8)
  int xcd = b & 7;
  int rc = (b - XBLK - TBLK) >> 3;
  int r = rc / CPB;
  int c = rc - r * CPB;
  int nlo = xcd * NRANGE, nhi = nlo + NRANGE;
  const int* dr = dst + (size_t)r * NE;
  const int* sr = src + (size_t)r * NE;
  int e0 = c * CHUNK + threadIdx.x * 4;
  #pragma unroll
  for (int u = 0; u < CHUNK / 1024; ++u) {
    int e = e0 + u * 1024;
    if (e + 3 < NE) {
      int4 d4 = *(const int4*)(dr + e);
      int4 s4 = *(const int4*)(sr + e);
      #pragma unroll
      for (int k = 0; k < 4; ++k) {
        int d = (k == 0) ? d4.x : (k == 1) ? d4.y : (k == 2) ? d4.z : d4.w;
        int s = (k == 0) ? s4.x : (k == 1) ? s4.y : (k == 2) ? s4.z : s4.w;
        if (d >= nlo && d < nhi) {
          int slot = atomicAdd(&cnt[r * NN + d], 1);
          if (slot < CAP)
            csrp[((size_t)r * NN + d) * CAP + slot] = (ushort)s;
        }
      }
    } else {
      for (int k = 0; k < 4; ++k) {
        int e2 = e + k;
        if (e2 < NE) {
          int d = dr[e2];
          if (d >= nlo && d < nhi) {
            int slot = atomicAdd(&cnt[r * NN + d], 1);
            if (slot < CAP)
              csrp[((size_t)r * NN + d) * CAP + slot] = (ushort)sr[e2];
          }
        }
      }
    }
  }
}

// ---------------- aggregation: one wave per (node, rel), unroll-4 ----------------
// Plain (cached) xa stores: with 4-seg phasing the ~100MB xa slice stays L3-resident
// for the immediately following GEMM pass (r15 lesson: nt stream thrashed L3).

__global__ __launch_bounds__(256) void k_agg(const ushort* __restrict__ xb,
                                             const ushort* __restrict__ csrp,
                                             const int* __restrict__ cnt,
                                             ushort* __restrict__ xa,
                                             long strideR, int r0) {
  int wid = threadIdx.x >> 6, lane = threadIdx.x & 63;
  int n = blockIdx.x * 4 + wid;
  int r = r0 + blockIdx.y;
  if (n >= NN) return;
  int dg = cnt[r * NN + n];
  int m = min(dg, CAP);
  const ushort* lst = csrp + ((size_t)r * NN + n) * CAP;
  float a0 = 0.f, a1 = 0.f, a2 = 0.f, a3 = 0.f;
  int j = 0;
  for (; j + 3 < m; j += 4) {
    int s0 = lst[j], s1 = lst[j + 1], s2 = lst[j + 2], s3 = lst[j + 3];
    ushort4 v0 = *(const ushort4*)(xb + (size_t)s0 * 256 + lane * 4);
    ushort4 v1 = *(const ushort4*)(xb + (size_t)s1 * 256 + lane * 4);
    ushort4 v2 = *(const ushort4*)(xb + (size_t)s2 * 256 + lane * 4);
    ushort4 v3 = *(const ushort4*)(xb + (size_t)s3 * 256 + lane * 4);
    a0 += (b2f(v0.x) + b2f(v1.x)) + (b2f(v2.x) + b2f(v3.x));
    a1 += (b2f(v0.y) + b2f(v1.y)) + (b2f(v2.y) + b2f(v3.y));
    a2 += (b2f(v0.z) + b2f(v1.z)) + (b2f(v2.z) + b2f(v3.z));
    a3 += (b2f(v0.w) + b2f(v1.w)) + (b2f(v2.w) + b2f(v3.w));
  }
  for (; j < m; ++j) {
    ushort4 v0 = *(const ushort4*)(xb + (size_t)lst[j] * 256 + lane * 4);
    a0 += b2f(v0.x); a1 += b2f(v0.y); a2 += b2f(v0.z); a3 += b2f(v0.w);
  }
  float inv = 1.f / (float)max(dg, 1);
  unsigned w0 = ((unsigned)f2b(a0 * inv)) | (((unsigned)f2b(a1 * inv)) << 16);
  unsigned w1 = ((unsigned)f2b(a2 * inv)) | (((unsigned)f2b(a3 * inv)) << 16);
  uint2v o; o[0] = w0; o[1] = w1;
  *(uint2v*)(xa + (size_t)(r - r0) * strideR + (size_t)n * 256 + lane * 4) = o;
}

// ---------------- GEMM (r12 structure): BM=128 x BN=256, counted-vmcnt pipeline ----------------
// A dbuf 2x16KB + Bs 32KB = 64KB, 2 blocks/CU. Both-sides XOR swizzle (r8-verified).

#define BK 64

__global__ __launch_bounds__(512, 4) void k_gemm(
    const ushort* __restrict__ xa, long strideR, int nseg,
    const ushort* __restrict__ xb8, const ushort* __restrict__ wb, int wseg0,
    const float* __restrict__ bias, float* __restrict__ out, int first, int final_) {
  __shared__ ushort As[2][128 * BK];  // 2 x 16 KB
  __shared__ ushort Bs[256 * BK];     // 32 KB
  int t = threadIdx.x;
  int lane = t & 63, wid = t >> 6;
  int wm = wid >> 2, wn = wid & 3;
  int i0 = blockIdx.x * 128;
  const int NT = nseg * 4;

  f32x4 acc[4][4];
  #pragma unroll
  for (int a = 0; a < 4; ++a)
    #pragma unroll
    for (int b = 0; b < 4; ++b) acc[a][b] = (f32x4){0.f, 0.f, 0.f, 0.f};

#define STAGE_A(stp, buf) do {                                                  \
    int s_ = (stp) >> 2; int kt_ = ((stp) & 3) * 64;                            \
    const ushort* A_ = (wseg0 + s_ < 8) ? (xa + (size_t)s_ * strideR) : xb8;    \
    _Pragma("unroll")                                                           \
    for (int it = 0; it < 2; ++it) {                                            \
      int c = it * 512 + t; int row = c >> 3, sg = c & 7;                       \
      int sgg = sg ^ (row & 7);                                                 \
      const ushort* ga = A_ + (size_t)(i0 + row) * 256 + kt_ + sgg * 8;         \
      __builtin_amdgcn_global_load_lds(                                         \
          (const __attribute__((address_space(1))) unsigned int*)ga,            \
          (__attribute__((address_space(3))) unsigned int*)(As[buf] + c * 8),   \
          16, 0, 0);                                                            \
    } } while (0)

#define STAGE_B(stp) do {                                                       \
    int s_ = (stp) >> 2; int kt_ = ((stp) & 3) * 64;                            \
    const ushort* W_ = wb + (size_t)(wseg0 + s_) * 65536;                       \
    _Pragma("unroll")                                                           \
    for (int it = 0; it < 4; ++it) {                                            \
      int c = it * 512 + t; int row = c >> 3, sg = c & 7;                       \
      int sgg = sg ^ (row & 7);                                                 \
      const ushort* gb = W_ + (size_t)row * 256 + kt_ + sgg * 8;                \
      __builtin_amdgcn_global_load_lds(                                         \
          (const __attribute__((address_space(1))) unsigned int*)gb,            \
          (__attribute__((address_space(3))) unsigned int*)(Bs + c * 8),        \
          16, 0, 0);                                                            \
    } } while (0)

  STAGE_A(0, 0);  // prologue
  int cur = 0;
  #pragma unroll 1
  for (int st = 0; st < NT; ++st) {
    __builtin_amdgcn_s_barrier();  // all waves done reading Bs / As[cur^1]
    STAGE_B(st);
    if (st + 1 < NT) {
      STAGE_A(st + 1, cur ^ 1);
      asm volatile("s_waitcnt vmcnt(2)" ::: "memory");  // A(cur)+B(cur) retired
    } else {
      asm volatile("s_waitcnt vmcnt(0)" ::: "memory");
    }
    __builtin_amdgcn_sched_barrier(0);
    __builtin_amdgcn_s_barrier();  // tiles visible to all waves
    __builtin_amdgcn_sched_barrier(0);
    const ushort* Ac = As[cur];
    #pragma unroll
    for (int kk = 0; kk < 2; ++kk) {
      int ko = kk * 32 + (lane >> 4) * 8;   // ushort offset within row
      int kb = ko * 2;                      // byte offset (16B-aligned)
      short8v a_frag[4], b_frag[4];
      #pragma unroll
      for (int mi = 0; mi < 4; ++mi) {
        int row = wm * 64 + mi * 16 + (lane & 15);
        int ba = row * 128 + (kb ^ ((row & 7) << 4));
        a_frag[mi] = *(const short8v*)((const char*)Ac + ba);
      }
      #pragma unroll
      for (int ni = 0; ni < 4; ++ni) {
        int row = wn * 64 + ni * 16 + (lane & 15);
        int ba = row * 128 + (kb ^ ((row & 7) << 4));
        b_frag[ni] = *(const short8v*)((const char*)Bs + ba);
      }
      #pragma unroll
      for (int mi = 0; mi < 4; ++mi)
        #pragma unroll
        for (int ni = 0; ni < 4; ++ni)
          acc[mi][ni] = __builtin_amdgcn_mfma_f32_16x16x32_bf16(
              a_frag[mi], b_frag[ni], acc[mi][ni], 0, 0, 0);
    }
    cur ^= 1;
  }
#undef STAGE_A
#undef STAGE_B

  // epilogue: C elem (col = lane&15, row = (lane>>4)*4 + reg)
  #pragma unroll
  for (int mi = 0; mi < 4; ++mi) {
    int rbase = i0 + wm * 64 + mi * 16 + ((lane >> 4) << 2);
    #pragma unroll
    for (int ni = 0; ni < 4; ++ni) {
      int col = wn * 64 + ni * 16 + (lane & 15);
      float bv = final_ ? bias[col] : 0.f;
      #pragma unroll
      for (int rg = 0; rg < 4; ++rg) {
        int gm = rbase + rg;
        if (gm < NN) {
          size_t o = (size_t)gm * 256 + col;
          float v = acc[mi][ni][rg];
          if (!first) v += out[o];
          if (final_) v = fmaxf(v + bv, 0.f);
          out[o] = v;
        }
      }
    }
  }
}

// ---------------- host ----------------

extern "C" void kernel_launch(void* const* d_in, const int* in_sizes, int n_in,
                              void* d_out, int out_size, void* d_ws, size_t ws_size,
                              hipStream_t stream) {
  const float* x = (const float*)d_in[0];
  const float* w = (const float*)d_in[1];
  const float* bias = (const float*)d_in[2];
  const float* lw = (const float*)d_in[3];
  const int* src = (const int*)d_in[4];
  const int* dst = (const int*)d_in[5];
  float* out = (float*)d_out;

  char* ws = (char*)d_ws;
  size_t off = 0;
  auto carve = [&](size_t bytes) {
    size_t o = off;
    off = (off + bytes + 255) & ~(size_t)255;
    return o;
  };
  int* cnt = (int*)(ws + carve((size_t)NR * NN * 4));
  ushort* csrp = (ushort*)(ws + carve((size_t)NR * NN * CAP * 2));
  ushort* wb = (ushort*)(ws + carve((size_t)9 * 65536 * 2));
  ushort* xb = (ushort*)(ws + carve((size_t)NPAD * 256 * 2));
  size_t base_bytes = off;
  ushort* xa = (ushort*)(ws + off);
  const size_t segb = (size_t)NPAD * 256 * 2;
  long strideR = (long)NPAD * 256;

  (void)hipMemsetAsync(cnt, 0, (size_t)NR * NN * 4, stream);
  k_prep<<<XBLK + TBLK + 8 * CPB * NR, 256, 0, stream>>>(x, w, lw, xb, wb,
                                                         src, dst, cnt, csrp);

  dim3 gemm_grid(NPAD / 128);
  if (ws_size >= base_bytes + 4 * segb) {
    // Two 4-segment phases: each phase's xa slice (~100MB) stays L3-resident
    // for its GEMM pass (and the x gather set stays warmer during agg).
    k_agg<<<dim3((NN + 3) / 4, 4), 256, 0, stream>>>(xb, csrp, cnt, xa, strideR, 0);
    k_gemm<<<gemm_grid, 512, 0, stream>>>(xa, strideR, 4, xb, wb, 0, bias, out, 1, 0);
    k_agg<<<dim3((NN + 3) / 4, 4), 256, 0, stream>>>(xb, csrp, cnt, xa, strideR, 4);
    k_gemm<<<gemm_grid, 512, 0, stream>>>(xa, strideR, 5, xb, wb, 4, bias, out, 0, 1);
  } else {
    // Fallback: one relation at a time.
    for (int r = 0; r < 8; ++r) {
      k_agg<<<dim3((NN + 3) / 4, 1), 256, 0, stream>>>(xb, csrp, cnt, xa, strideR, r);
      k_gemm<<<gemm_grid, 512, 0, stream>>>(xa, strideR, 1, xb, wb, r, bias, out,
                                            (r == 0) ? 1 : 0, 0);
    }
    k_gemm<<<gemm_grid, 512, 0, stream>>>(xa, strideR, 1, xb, wb, 8, bias, out, 0, 1);
  }
  (void)in_sizes; (void)n_in; (void)out_size;
}